// Round 5
// baseline (754.871 us; speedup 1.0000x reference)
//
#include <hip/hip_runtime.h>

#define NB 4096   // B
#define NS 200    // S
#define NP 8      // P
#define NF 64     // F

#define RB 5      // batch rows per block
#define LPS 50    // lane-slices per row (RB*LPS = 250 active threads)

// u LDS layout: group of 8 floats per f, XOR-swizzled within group:
//   u_lds[g][f*8 + (p ^ (f&7))] = u[p][f]
// Staging writes (lanes vary f, p fixed) then spread over all 32 banks (<=2-way,
// free per m136). Reads are wave-uniform(ish) b128; since read-time f&7 == j is
// a compile-time constant, the permutation folds into accumulator indices.

__global__ __launch_bounds__(256, 4) void cf_kernel(
    const int*   __restrict__ user,
    const int*   __restrict__ items,
    const float* __restrict__ user_factors,   // [N_USERS][P][F] fp32
    const float* __restrict__ item_factors,   // [N_ITEMS][F]    fp32
    float* __restrict__ out_pred,             // [B][S]          fp32
    float* __restrict__ out_scores)           // [B][S][P]       fp32
{
    __shared__ float u_lds[RB][NF * NP];      // 10 KB

    const int tid  = threadIdx.x;
    const int b0   = blockIdx.x * RB;
    const int rows = min(RB, NB - b0);

    // ---- stage user factors: coalesced read, swizzled transposed write ----
    for (int e = tid; e < rows * (NP * NF); e += 256) {
        int g = e >> 9;            // /512
        int q = e & 511;
        int uid = user[b0 + g];
        float w = user_factors[(size_t)uid * (NP * NF) + q];
        int p = q >> 6, f = q & 63;
        u_lds[g][f * 8 + (p ^ (f & 7))] = w;
    }
    __syncthreads();

    const int g = tid / LPS;
    const int l = tid - g * LPS;
    if (g >= rows) return;         // also kills tid 250..255
    const int b = b0 + g;
    const float* __restrict__ ug = u_lds[g];

    // 2 pairs of items; per pair, per half-row: one 128B line-burst per item
    // (8 concurrent float4 loads -> line fetched once), then u-sweep from LDS.
    #pragma unroll
    for (int pair = 0; pair < 2; ++pair) {
        const int sa = l + LPS * (2 * pair);
        const int sb = sa + LPS;
        const int ia = items[b * NS + sa];
        const int ib = items[b * NS + sb];
        const float4* pa = (const float4*)(item_factors + (size_t)ia * NF);
        const float4* pb = (const float4*)(item_factors + (size_t)ib * NF);

        float aa[NP], ab[NP];
        #pragma unroll
        for (int p = 0; p < NP; ++p) { aa[p] = 0.f; ab[p] = 0.f; }

        #pragma unroll
        for (int half = 0; half < 2; ++half) {
            float4 va[8], vb[8];   // 64 VGPRs live, 16 loads in flight
            #pragma unroll
            for (int i = 0; i < 8; ++i) va[i] = pa[half * 8 + i];
            #pragma unroll
            for (int i = 0; i < 8; ++i) vb[i] = pb[half * 8 + i];

            #pragma unroll
            for (int c = 0; c < 4; ++c) {
                #pragma unroll
                for (int j = 0; j < 8; ++j) {
                    const int f = half * 32 + c * 8 + j;     // f&7 == j
                    const float4* up = (const float4*)&ug[f * 8];
                    float4 ua = up[0];
                    float4 ub = up[1];
                    float xa = ((const float*)va)[c * 8 + j];  // folds at compile time
                    float xb = ((const float*)vb)[c * 8 + j];
                    // component i of (ua,ub) holds u[p = i^j]
                    aa[0 ^ j] += xa * ua.x;  aa[1 ^ j] += xa * ua.y;
                    aa[2 ^ j] += xa * ua.z;  aa[3 ^ j] += xa * ua.w;
                    aa[4 ^ j] += xa * ub.x;  aa[5 ^ j] += xa * ub.y;
                    aa[6 ^ j] += xa * ub.z;  aa[7 ^ j] += xa * ub.w;
                    ab[0 ^ j] += xb * ua.x;  ab[1 ^ j] += xb * ua.y;
                    ab[2 ^ j] += xb * ua.z;  ab[3 ^ j] += xb * ua.w;
                    ab[4 ^ j] += xb * ub.x;  ab[5 ^ j] += xb * ub.y;
                    ab[6 ^ j] += xb * ub.z;  ab[7 ^ j] += xb * ub.w;
                }
            }
        }

        // ---- softmax + pred + store for both items ----
        #pragma unroll
        for (int which = 0; which < 2; ++which) {
            float* a = which ? ab : aa;
            const int s = which ? sb : sa;
            float m = a[0];
            #pragma unroll
            for (int p = 1; p < NP; ++p) m = fmaxf(m, a[p]);
            float e[NP], sum = 0.f;
            #pragma unroll
            for (int p = 0; p < NP; ++p) { e[p] = __expf(a[p] - m); sum += e[p]; }
            float inv = 1.f / sum;

            float sc[NP], pred = 0.f;
            #pragma unroll
            for (int p = 0; p < NP; ++p) {
                sc[p] = e[p] * inv;
                pred += sc[p] * a[p];
            }

            out_pred[b * NS + s] = pred;
            float4* op = (float4*)(out_scores + (size_t)(b * NS + s) * NP);
            op[0] = make_float4(sc[0], sc[1], sc[2], sc[3]);
            op[1] = make_float4(sc[4], sc[5], sc[6], sc[7]);
        }
    }
}

extern "C" void kernel_launch(void* const* d_in, const int* in_sizes, int n_in,
                              void* d_out, int out_size, void* d_ws, size_t ws_size,
                              hipStream_t stream) {
    const int*   user         = (const int*)d_in[0];
    const int*   items        = (const int*)d_in[1];
    const float* user_factors = (const float*)d_in[2];
    const float* item_factors = (const float*)d_in[3];

    float* out_pred   = (float*)d_out;
    float* out_scores = out_pred + (size_t)NB * NS;   // outputs concatenated: pred, scores

    const int grid = (NB + RB - 1) / RB;   // 820
    cf_kernel<<<grid, 256, 0, stream>>>(user, items, user_factors, item_factors,
                                        out_pred, out_scores);
}